// Round 1
// 765.064 us; speedup vs baseline: 1.1079x; 1.1079x over previous
//
#include <hip/hip_runtime.h>
#include <hip/hip_bf16.h>
#include <math.h>

// Problem constants
constexpr int B = 32, S = 2048, D = 1024, E = 16, TK = 4, O = 1024;
constexpr int KD = TK * D;       // 4096
constexpr int KS = 8;            // split-K factor for grouped GEMMs

// ---------------------------------------------------------------------------
// K1: gating logits, transposed out: logitsT[b][e][s] = x[b,s,:]·Wg[:,e]+bg[e]
// Rewritten for occupancy + latency hiding:
//   grid = B*S/64 = 1024 blocks (4 blocks/CU -> 16 waves/CU, was 4 waves/CU).
//   Each block: 64 rows x 4 waves; wave w handles a 256-column slice of D.
//   8-deep float4 batching -> 8 outstanding loads/thread (~128 KB in
//   flight/CU vs ~10 KB needed at 6.3 TB/s).
//   Weight addresses are wave-uniform (readfirstlane on wave id) -> s_load.
//   Cross-wave reduction through padded LDS, coalesced 256 B stores.
// ---------------------------------------------------------------------------
__global__ __launch_bounds__(256) void k_logits(
    const float* __restrict__ x, const float* __restrict__ Wg,
    const float* __restrict__ bg, float* __restrict__ logitsT) {
  int tid = threadIdx.x;
  int lane = tid & 63;
  int wid = __builtin_amdgcn_readfirstlane(tid >> 6);   // 0..3, wave-uniform
  int row0 = blockIdx.x * 64;
  int row = row0 + lane;                                // global token row
  const float* xr = x + (size_t)row * D + wid * 256;
  const float* wg = Wg + (size_t)wid * 256 * E;         // scalar base
  float acc[E];
#pragma unroll
  for (int e = 0; e < E; e++) acc[e] = 0.f;
  for (int it = 0; it < 64; it += 8) {
    float4 xv[8];
#pragma unroll
    for (int u = 0; u < 8; u++)
      xv[u] = *(const float4*)(xr + (it + u) * 4);
#pragma unroll
    for (int u = 0; u < 8; u++) {
      const float* w0 = wg + (size_t)(it + u) * 4 * E;  // wave-uniform
#pragma unroll
      for (int e = 0; e < E; e++)
        acc[e] += xv[u].x * w0[e] + xv[u].y * w0[E + e] +
                  xv[u].z * w0[2 * E + e] + xv[u].w * w0[3 * E + e];
    }
  }
  // cross-wave reduce: [part][row][e], +17 pad -> stride 17 coprime 32 banks
  __shared__ float red[4][64][17];
#pragma unroll
  for (int e = 0; e < E; e++) red[wid][lane][e] = acc[e];
  __syncthreads();
  int b = row0 >> 11;          // row0 / S
  int s0 = row0 & (S - 1);
#pragma unroll
  for (int i = 0; i < 4; i++) {
    int e = wid + i * 4;       // wave w writes e = w, w+4, w+8, w+12
    float v = red[0][lane][e] + red[1][lane][e] + red[2][lane][e] +
              red[3][lane][e] + bg[e];
    logitsT[((size_t)b * E + e) * S + s0 + lane] = v;   // 256 B coalesced
  }
}

// ---------------------------------------------------------------------------
// K2: per (b,e): softmax-over-tokens denominator + top-4 (value-desc, tie->low idx)
// One block per (b,e).  (unchanged — not a measured bottleneck)
// ---------------------------------------------------------------------------
__global__ __launch_bounds__(256) void k_topk(
    const float* __restrict__ logitsT, int* __restrict__ tIdx,
    float* __restrict__ tVal) {
  int be = blockIdx.x;                       // 0 .. B*E-1
  const float* lrow = logitsT + (size_t)be * S;
  __shared__ float sv[S];
  __shared__ float red[256];
  __shared__ int redi[256];
  int t = threadIdx.x;
  for (int i = t; i < S; i += 256) sv[i] = lrow[i];
  __syncthreads();
  // global max
  float m = -1e30f;
  for (int i = t; i < S; i += 256) m = fmaxf(m, sv[i]);
  red[t] = m;
  __syncthreads();
  for (int off = 128; off > 0; off >>= 1) {
    if (t < off) red[t] = fmaxf(red[t], red[t + off]);
    __syncthreads();
  }
  float gmax = red[0];
  __syncthreads();
  // sum of exp
  float se = 0.f;
  for (int i = t; i < S; i += 256) se += expf(sv[i] - gmax);
  red[t] = se;
  __syncthreads();
  for (int off = 128; off > 0; off >>= 1) {
    if (t < off) red[t] += red[t + off];
    __syncthreads();
  }
  float sumexp = red[0];
  __syncthreads();
  // 4 argmax passes
  for (int j = 0; j < 4; j++) {
    float bv = -1e30f;
    int bi = S;
    for (int i = t; i < S; i += 256) {
      float v = sv[i];
      if (v > bv || (v == bv && i < bi)) { bv = v; bi = i; }
    }
    red[t] = bv;
    redi[t] = bi;
    __syncthreads();
    for (int off = 128; off > 0; off >>= 1) {
      if (t < off) {
        float v2 = red[t + off];
        int i2 = redi[t + off];
        if (v2 > red[t] || (v2 == red[t] && i2 < redi[t])) {
          red[t] = v2;
          redi[t] = i2;
        }
      }
      __syncthreads();
    }
    if (t == 0) {
      tIdx[be * TK + j] = redi[0];
      tVal[be * TK + j] = expf(red[0] - gmax) / sumexp;
      sv[redi[0]] = -1e30f;   // mask for next pass
    }
    __syncthreads();
  }
}

// ---------------------------------------------------------------------------
// K3: gather+scale tokens into K-major transposed activations:
//   inpT[e][j*D + d][b] = x[b, idx[b,e,j], d] * val[b,e,j]
// (unchanged)
// ---------------------------------------------------------------------------
__global__ __launch_bounds__(256) void k_gather(
    const float* __restrict__ x, const int* __restrict__ tIdx,
    const float* __restrict__ tVal, float* __restrict__ inpT) {
  int ej = blockIdx.x;
  int e = ej / TK, j = ej % TK;
  int d0 = blockIdx.y * 256;
  __shared__ float st[32][257];
  int tid = threadIdx.x;
  int dt = tid % 64;   // float4 index along d
  int bq = tid / 64;   // 0..3
  for (int bi = 0; bi < 8; bi++) {
    int b = bq * 8 + bi;   // wave-uniform
    int row = tIdx[(b * E + e) * TK + j];
    float v = tVal[(b * E + e) * TK + j];
    float4 xv = *(const float4*)(x + ((size_t)b * S + row) * D + d0 + dt * 4);
    st[b][dt * 4 + 0] = xv.x * v;
    st[b][dt * 4 + 1] = xv.y * v;
    st[b][dt * 4 + 2] = xv.z * v;
    st[b][dt * 4 + 3] = xv.w * v;
  }
  __syncthreads();
  size_t base = ((size_t)e * TK + j) * D + d0;   // k-index base
  for (int c = 0; c < 32; c++) {
    int idx = c * 256 + tid;
    int drel = idx / 32, b = idx % 32;
    inpT[(base + drel) * 32 + b] = st[b][drel];
  }
}

// ---------------------------------------------------------------------------
// K4: split-K grouped GEMM partial:  part[ks][e][n][m] = sum_k AT[e][k][m]*W[e][k][n]
// Rewritten: 256-thread blocks (4 waves). Lane owns 4 consecutive n
// (float4 W loads -> 1 KB/wave per instr instead of 256 B). Wave w owns
// m-rows [8w, 8w+8) -> acc[8][4]; the 4 waves stream the SAME W lines,
// sharing them through L1. A reads are wave-uniform scalar (s_load,
// readfirstlane-forced). 8-deep k batching -> ~64 KB in flight/CU.
// ---------------------------------------------------------------------------
template <int KC>
__global__ __launch_bounds__(256) void k_gemm_part(
    const float* __restrict__ AT,   // [E][Ktot][32]
    const float* __restrict__ W,    // [E][Ktot][O]
    float* __restrict__ part,       // [KS][E][O][32]
    int Ktot) {
  int e = blockIdx.x, nt = blockIdx.y, ks = blockIdx.z;
  int tid = threadIdx.x;
  int lane = tid & 63;
  int m0 = __builtin_amdgcn_readfirstlane((tid >> 6) * 8);  // 0,8,16,24
  int n0 = nt * 256 + lane * 4;
  int k0 = ks * KC;
  const float* a = AT + ((size_t)e * Ktot + k0) * 32 + m0;  // wave-uniform
  const float* w = W + ((size_t)e * Ktot + k0) * O + n0;
  float acc[8][4];
#pragma unroll
  for (int m = 0; m < 8; m++)
#pragma unroll
    for (int q = 0; q < 4; q++) acc[m][q] = 0.f;
  for (int k = 0; k < KC; k += 8) {
    float4 wv[8];
#pragma unroll
    for (int u = 0; u < 8; u++)
      wv[u] = *(const float4*)(w + (size_t)(k + u) * O);
#pragma unroll
    for (int u = 0; u < 8; u++) {
      const float* ar = a + (size_t)(k + u) * 32;           // s_load_dwordx8
#pragma unroll
      for (int m = 0; m < 8; m++) {
        float av = ar[m];
        acc[m][0] += av * wv[u].x;
        acc[m][1] += av * wv[u].y;
        acc[m][2] += av * wv[u].z;
        acc[m][3] += av * wv[u].w;
      }
    }
  }
  // store: per n (4), two float4 covering m0..m0+7 (32 B contiguous / lane)
  float* pb = part + (((size_t)ks * E + e) * O + n0) * 32 + m0;
#pragma unroll
  for (int ni = 0; ni < 4; ni++) {
    *(float4*)(pb + ni * 32) =
        make_float4(acc[0][ni], acc[1][ni], acc[2][ni], acc[3][ni]);
    *(float4*)(pb + ni * 32 + 4) =
        make_float4(acc[4][ni], acc[5][ni], acc[6][ni], acc[7][ni]);
  }
}

// ---------------------------------------------------------------------------
// K5: reduce split-K partials + bias + optional ReLU -> transposed act layout
//   outT[e][n][m], processed as float4 over m.  (unchanged)
// ---------------------------------------------------------------------------
__global__ __launch_bounds__(256) void k_reduce_act(
    const float* __restrict__ part, const float* __restrict__ bias,
    float* __restrict__ outT, int relu) {
  size_t g = (size_t)blockIdx.x * 256 + threadIdx.x;   // float4 index
  const size_t stride4 = (size_t)E * O * 32 / 4;       // 131072
  const float4* p4 = (const float4*)part;
  float4 s = p4[g];
#pragma unroll
  for (int ks = 1; ks < KS; ks++) {
    float4 v = p4[(size_t)ks * stride4 + g];
    s.x += v.x; s.y += v.y; s.z += v.z; s.w += v.w;
  }
  size_t el = g * 4;
  int n = (int)((el / 32) % O);
  int e = (int)(el / ((size_t)32 * O));
  float bv = bias[e * O + n];
  s.x += bv; s.y += bv; s.z += bv; s.w += bv;
  if (relu) {
    s.x = fmaxf(s.x, 0.f); s.y = fmaxf(s.y, 0.f);
    s.z = fmaxf(s.z, 0.f); s.w = fmaxf(s.w, 0.f);
  }
  ((float4*)outT)[g] = s;
}

// ---------------------------------------------------------------------------
// K6: final reduce + bias, transposed through LDS to d_out[b][e][o]
// (unchanged)
// ---------------------------------------------------------------------------
__global__ __launch_bounds__(256) void k_final(
    const float* __restrict__ part, const float* __restrict__ bias,
    float* __restrict__ out) {
  int e = blockIdx.x;
  int o0 = blockIdx.y * 64;
  __shared__ float sd[64][33];
  int tid = threadIdx.x;
  const size_t stride = (size_t)E * O * 32;
  for (int c = 0; c < 8; c++) {
    int idx = c * 256 + tid;          // 0..2047
    int orel = idx / 32, b = idx % 32;
    size_t off = ((size_t)e * O + o0 + orel) * 32 + b;
    float s = part[off];
#pragma unroll
    for (int ks = 1; ks < KS; ks++) s += part[(size_t)ks * stride + off];
    sd[orel][b] = s + bias[e * O + o0 + orel];
  }
  __syncthreads();
  for (int c = 0; c < 8; c++) {
    int idx = c * 256 + tid;
    int b = idx / 64, orr = idx % 64;
    out[((size_t)b * E + e) * O + o0 + orr] = sd[orr][b];
  }
}

// ---------------------------------------------------------------------------
extern "C" void kernel_launch(void* const* d_in, const int* in_sizes, int n_in,
                              void* d_out, int out_size, void* d_ws,
                              size_t ws_size, hipStream_t stream) {
  (void)in_sizes; (void)n_in; (void)out_size; (void)ws_size;
  const float* x  = (const float*)d_in[0];
  const float* Wg = (const float*)d_in[1];
  const float* bg = (const float*)d_in[2];
  const float* W1 = (const float*)d_in[3];
  const float* b1 = (const float*)d_in[4];
  const float* W2 = (const float*)d_in[5];
  const float* b2 = (const float*)d_in[6];
  const float* W3 = (const float*)d_in[7];
  const float* b3 = (const float*)d_in[8];
  float* out = (float*)d_out;

  char* ws = (char*)d_ws;
  float* logitsT = (float*)ws;                                   // 4 MB
  int*   tIdx    = (int*)(ws + (4u << 20));                      // 8 KB
  float* tVal    = (float*)(ws + (4u << 20) + (8u << 10));       // 8 KB
  float* inpT    = (float*)(ws + (4u << 20) + (64u << 10));      // 8 MB
  float* part    = (float*)(ws + (12u << 20) + (64u << 10));     // 16 MB
  float* h1T     = (float*)(ws + (28u << 20) + (64u << 10));     // 2 MB
  float* h2T     = (float*)(ws + (30u << 20) + (64u << 10));     // 2 MB

  // 1) gating logits (transposed [B,E,S]) — 1024 blocks, 4 col-parts/row
  k_logits<<<B * S / 64, 256, 0, stream>>>(x, Wg, bg, logitsT);
  // 2) softmax-over-tokens + top-4 per (b,e)
  k_topk<<<B * E, 256, 0, stream>>>(logitsT, tIdx, tVal);
  // 3) gather+scale -> inpT [E][4096][32]
  k_gather<<<dim3(E * TK, D / 256), 256, 0, stream>>>(x, tIdx, tVal, inpT);
  // 4) layer 1: [32,4096] @ W1[e] -> h1T
  k_gemm_part<KD / KS><<<dim3(E, O / 256, KS), 256, 0, stream>>>(inpT, W1, part, KD);
  k_reduce_act<<<(E * O * 32 / 4) / 256, 256, 0, stream>>>(part, b1, h1T, 1);
  // 5) layer 2
  k_gemm_part<O / KS><<<dim3(E, O / 256, KS), 256, 0, stream>>>(h1T, W2, part, O);
  k_reduce_act<<<(E * O * 32 / 4) / 256, 256, 0, stream>>>(part, b2, h2T, 1);
  // 6) layer 3 + transpose to [B,E,O]
  k_gemm_part<O / KS><<<dim3(E, O / 256, KS), 256, 0, stream>>>(h2T, W3, part, O);
  k_final<<<dim3(E, O / 64), 256, 0, stream>>>(part, b3, out);
}